// Round 7
// baseline (489.196 us; speedup 1.0000x reference)
//
#include <hip/hip_runtime.h>

typedef _Float16 half8 __attribute__((ext_vector_type(8)));
typedef __attribute__((ext_vector_type(4))) float f32x4;

#define C_DIM 512
#define S_DIM 4096
#define NCOL 165      // 3 * sum(k=1..10)
#define NCOLP 176     // padded to 11 * 16
#define M_OUT 64
#define NCHUNK 16     // 512 / 32
#define YST 180       // epilogue Y row stride (words)
#define YSLOT 2880    // 16 * YST

struct WP { const float* w[10]; };

// Pack weights into B^T fp16: bt[col][c], col = 3*k(k-1)/2 + t*3 + p. RNE cast.
__global__ __launch_bounds__(256) void prep_kernel(WP wp, _Float16* bt) {
  int idx = blockIdx.x * 256 + threadIdx.x;   // 176*512 threads exactly
  int col = idx >> 9;
  int c = idx & 511;
  float v = 0.f;
  if (col < NCOL) {
    int kw = 1, base = 0;
    while (col >= base + 3 * kw) { base += 3 * kw; ++kw; }
    int rem = col - base;
    int t = rem / 3, p = rem - 3 * t;
    v = wp.w[kw - 1][(t * C_DIM + c) * 3 + p];   // w_k layout (k, C, P)
  }
  bt[col * C_DIM + c] = (_Float16)v;            // RNE
}

__global__ __launch_bounds__(256, 4) void conv_kernel(const float* __restrict__ x,
                                                      const _Float16* __restrict__ bt,
                                                      float* __restrict__ out) {
  // NO LDS in the main loop — A-frags load straight from global (L1/L2-served),
  // B-frags from the 180 KB L2-resident bt. Zero barriers until the epilogue.
  // LDS only for the epilogue d-sum: 2 slots of 16 x YST fp32 = 23040 B.
  __shared__ __align__(16) float Ys[2 * YSLOT];

  const int tid = threadIdx.x;
  const int b = blockIdx.x >> 6;        // 64 tiles per batch
  const int tile = blockIdx.x & 63;
  const int s0 = tile * M_OUT;
  const int sBase = s0 - 16;            // halo start
  const int wave = tid >> 6;
  const int lane = tid & 63;
  const int l15 = lane & 15;
  const int quad = lane >> 4;
  const int n0 = wave * 3;              // n-tile split 3/3/3/2
  const int nmine = (wave < 3) ? 3 : 2;
  const bool t0 = (tile == 0);          // tile 0: m=0 sub-tile is all causal-pad zeros

  // --- per-wave B fragment pointers (global, L2-resident) ---
  const half8* bptr[3];
#pragma unroll
  for (int nn = 0; nn < 3; ++nn) {
    int cr = (n0 + nn) * 16 + l15;
    bptr[nn] = (const half8*)&bt[(nn < nmine ? cr : l15) * C_DIM + quad * 8];
  }

  // --- per-lane A row pointers: A-frag[m] row = sBase + m*16 + l15, k = quad*8+j ---
  const float* aP[5];
#pragma unroll
  for (int m = 0; m < 5; ++m) {
    int s = sBase + m * 16 + l15;
    if (s < 0) s = 0;                   // only hit for tile0/m0, which is skipped
    aP[m] = &x[((size_t)(b * S_DIM + s)) * C_DIM + quad * 8];
  }

  f32x4 acc[5][3];
#pragma unroll
  for (int m = 0; m < 5; ++m)
#pragma unroll
    for (int n = 0; n < 3; ++n) acc[m][n] = (f32x4){0.f, 0.f, 0.f, 0.f};

#pragma unroll 4
  for (int ch = 0; ch < NCHUNK; ++ch) {
    half8 bfr[3];
#pragma unroll
    for (int nn = 0; nn < 3; ++nn)
      if (nn < nmine) bfr[nn] = bptr[nn][ch * 4];   // ch*32 halves
#pragma unroll
    for (int m = 0; m < 5; ++m) {
      if (m == 0 && t0) continue;       // causal zero-pad rows: acc[0] stays 0
      const f32x4* ap = (const f32x4*)(aP[m] + ch * 32);
      f32x4 a0 = ap[0];
      f32x4 a1 = ap[1];
      half8 ah = {(_Float16)a0[0], (_Float16)a0[1], (_Float16)a0[2], (_Float16)a0[3],
                  (_Float16)a1[0], (_Float16)a1[1], (_Float16)a1[2], (_Float16)a1[3]};
#pragma unroll
      for (int nn = 0; nn < 3; ++nn)
        if (nn < nmine)
          acc[m][nn] = __builtin_amdgcn_mfma_f32_16x16x32_f16(ah, bfr[nn], acc[m][nn], 0, 0, 0);
    }
  }

  // ---- epilogue: d-sum + relu via LDS, ping-pong 16 x YST fp32 slots ----
  // C/D layout: col = lane&15 (global col = (n0+nn)*16 + l15), row = quad*4 + reg.
#pragma unroll
  for (int i = 1; i <= 4; ++i) {
    if (i == 1) {
#pragma unroll
      for (int nn = 0; nn < 3; ++nn)
        if (nn < nmine)
#pragma unroll
          for (int r = 0; r < 4; ++r)
            Ys[0 * YSLOT + (quad * 4 + r) * YST + (n0 + nn) * 16 + l15] = acc[0][nn][r];
    }
#pragma unroll
    for (int nn = 0; nn < 3; ++nn)
      if (nn < nmine)
#pragma unroll
        for (int r = 0; r < 4; ++r)
          Ys[(i & 1) * YSLOT + (quad * 4 + r) * YST + (n0 + nn) * 16 + l15] = acc[i][nn][r];
    __syncthreads();
    for (int o = tid; o < 480; o += 256) {
      int r = o / 30;
      int j = o - 30 * r;
      int kw = j / 3 + 1;
      int p = j - (kw - 1) * 3;
      int base = 3 * (kw * (kw - 1)) / 2;
      float sum = 0.f;
      for (int d = 0; d < kw; ++d) {
        int rr = r - d;
        int slot = (rr >= 0) ? (i & 1) : ((i ^ 1) & 1);
        int lr = (rr >= 0) ? rr : (16 + rr);
        int colv = base + (kw - 1 - d) * 3 + p;
        sum += Ys[slot * YSLOT + lr * YST + colv];
      }
      int s = s0 + 16 * (i - 1) + r;
      out[((size_t)(b * S_DIM + s)) * 30 + j] = fmaxf(sum, 0.f);
    }
    __syncthreads();
  }
}

extern "C" void kernel_launch(void* const* d_in, const int* in_sizes, int n_in,
                              void* d_out, int out_size, void* d_ws, size_t ws_size,
                              hipStream_t stream) {
  const float* x = (const float*)d_in[0];
  WP wp;
  for (int k = 0; k < 10; ++k) wp.w[k] = (const float*)d_in[k + 1];
  _Float16* bt = (_Float16*)d_ws;                  // 176*512*2 B = 180224 B
  prep_kernel<<<NCOLP * C_DIM / 256, 256, 0, stream>>>(wp, bt);
  conv_kernel<<<32 * (S_DIM / M_OUT), 256, 0, stream>>>(x, bt, (float*)d_out);
}

// Round 8
// 403.966 us; speedup vs baseline: 1.2110x; 1.2110x over previous
//
#include <hip/hip_runtime.h>

typedef _Float16 half8 __attribute__((ext_vector_type(8)));
typedef __attribute__((ext_vector_type(4))) float f32x4;

#define C_DIM 512
#define S_DIM 4096
#define NCOL 165      // 3 * sum(k=1..10)
#define NCOLP 176     // padded to 11 * 16
#define M_OUT 64
#define ROWS 80       // 16 halo + 64 output rows
#define BK 64         // k per chunk (2 MFMA K-steps)
#define NCHUNK 8      // 512 / 64
#define LDH 72        // LDS row stride in halves (64 data + 8 pad) -> even bank distribution
#define BUFB 11520    // bytes per A buffer: 80 * 72 * 2
#define YST 180       // epilogue Y row stride (words)
#define YSLOT 2880    // 16 * YST

struct WP { const float* w[10]; };

// Pack weights into B^T fp16: bt[col][c], col = 3*k(k-1)/2 + t*3 + p. RNE cast.
__global__ __launch_bounds__(256) void prep_kernel(WP wp, _Float16* bt) {
  int idx = blockIdx.x * 256 + threadIdx.x;   // 176*512 threads exactly
  int col = idx >> 9;
  int c = idx & 511;
  float v = 0.f;
  if (col < NCOL) {
    int kw = 1, base = 0;
    while (col >= base + 3 * kw) { base += 3 * kw; ++kw; }
    int rem = col - base;
    int t = rem / 3, p = rem - 3 * t;
    v = wp.w[kw - 1][(t * C_DIM + c) * 3 + p];   // w_k layout (k, C, P)
  }
  bt[col * C_DIM + c] = (_Float16)v;            // RNE
}

// LDS-visibility barrier: drains lgkm only; global loads stay in flight.
__device__ __forceinline__ void barrier_lgkm() {
  __asm__ volatile("s_waitcnt lgkmcnt(0)\n\ts_barrier" ::: "memory");
}

__global__ __launch_bounds__(256, 4) void conv_kernel(const float* __restrict__ x,
                                                      const _Float16* __restrict__ bt,
                                                      float* __restrict__ out) {
  // LDS: fp16 A double buffer 2 x 11520 B = 23040 B == epilogue overlay size.
  __shared__ __align__(16) unsigned char smem[2 * BUFB];
  float* Ys = (float*)smem;

  const int tid = threadIdx.x;
  const int b = blockIdx.x >> 6;        // 64 tiles per batch
  const int tile = blockIdx.x & 63;
  const int s0 = tile * M_OUT;
  const int sBase = s0 - 16;            // halo start
  const int wave = tid >> 6;
  const int lane = tid & 63;
  const int l15 = lane & 15;
  const int quad = lane >> 4;
  const int n0 = wave * 3;              // n-tile split 3/3/3/2
  const int nmine = (wave < 3) ? 3 : 2;

  // --- per-wave B fragment pointers (global, L1/L2-resident) ---
  const half8* bptr[3];
#pragma unroll
  for (int nn = 0; nn < 3; ++nn) {
    int cr = (n0 + nn) * 16 + l15;
    bptr[nn] = (const half8*)&bt[(nn < nmine ? cr : l15) * C_DIM + quad * 8];
  }

  // --- A staging geometry: 640 slots (row, q of 8 floats), 2.5 per thread ---
  const float4* aptr[3];
  bool aexists[3], avalid[3];
  int arow[3], aq[3];
#pragma unroll
  for (int i = 0; i < 3; ++i) {
    int idx = tid + i * 256;
    aexists[i] = (idx < 640);
    arow[i] = idx >> 3;
    aq[i] = idx & 7;
    int s = sBase + arow[i];
    avalid[i] = aexists[i] && (s >= 0);
    aptr[i] = (const float4*)&x[((size_t)(b * S_DIM + (s < 0 ? 0 : s))) * C_DIM + aq[i] * 8];
  }

  float4 pf[3][2];                      // per-slot 8 floats, staged one chunk ahead
  half8 bfr[3][2];                      // B frags for current chunk (kk = 0,1)
  f32x4 acc[5][3];
#pragma unroll
  for (int m = 0; m < 5; ++m)
#pragma unroll
    for (int n = 0; n < 3; ++n) acc[m][n] = (f32x4){0.f, 0.f, 0.f, 0.f};

  auto loadA = [&](int ch) {            // chunk ch spans floats [ch*64, ch*64+64) per row
#pragma unroll
    for (int i = 0; i < 3; ++i) {
      if (avalid[i]) {
        pf[i][0] = aptr[i][ch * 16];    // ch*64 floats = ch*16 float4
        pf[i][1] = aptr[i][ch * 16 + 1];
      } else {
        pf[i][0] = make_float4(0.f, 0.f, 0.f, 0.f);
        pf[i][1] = make_float4(0.f, 0.f, 0.f, 0.f);
      }
    }
  };
  auto cvtWrite = [&](int buf) {        // fp32x8 -> fp16x8 (RNE), one ds_write_b128 per slot
    _Float16* Ah = (_Float16*)(smem + buf * BUFB);
#pragma unroll
    for (int i = 0; i < 3; ++i) {
      if (aexists[i]) {
        half8 h = {(_Float16)pf[i][0].x, (_Float16)pf[i][0].y,
                   (_Float16)pf[i][0].z, (_Float16)pf[i][0].w,
                   (_Float16)pf[i][1].x, (_Float16)pf[i][1].y,
                   (_Float16)pf[i][1].z, (_Float16)pf[i][1].w};
        *(half8*)&Ah[arow[i] * LDH + aq[i] * 8] = h;
      }
    }
  };
  auto loadB = [&](int ch) {
#pragma unroll
    for (int nn = 0; nn < 3; ++nn)
      if (nn < nmine) {
        bfr[nn][0] = bptr[nn][ch * 8];       // k = ch*64 + quad*8
        bfr[nn][1] = bptr[nn][ch * 8 + 4];   // k = ch*64 + 32 + quad*8
      }
  };

  // ---------- prologue ----------
  loadA(0);
  cvtWrite(0);
  loadB(0);
  loadA(1);
  barrier_lgkm();

#pragma unroll
  for (int ch = 0; ch < NCHUNK; ++ch) {
    const _Float16* Ah = (const _Float16*)(smem + (ch & 1) * BUFB);
#pragma unroll
    for (int kk = 0; kk < 2; ++kk) {
#pragma unroll
      for (int m = 0; m < 5; ++m) {
        half8 a = *(const half8*)&Ah[(m * 16 + l15) * LDH + kk * 32 + quad * 8];
#pragma unroll
        for (int nn = 0; nn < 3; ++nn)
          if (nn < nmine)
            acc[m][nn] = __builtin_amdgcn_mfma_f32_16x16x32_f16(a, bfr[nn][kk], acc[m][nn], 0, 0, 0);
      }
    }
    if (ch < NCHUNK - 1) {
      loadB(ch + 1);                    // issued after last use of bfr; ~barrier+A-read gap to next use
      cvtWrite((ch + 1) & 1);           // pf(ch+1) was issued a full chunk (~>1200 cyc) ago
      if (ch < NCHUNK - 2) loadA(ch + 2);
      barrier_lgkm();                   // single LDS-only barrier per chunk
    }
  }

  __syncthreads();                      // full drain before overlaying A bufs with Ys

  // ---- epilogue: d-sum + relu via LDS, ping-pong 16 x YST fp32 slots ----
  // C/D layout: col = lane&15 (global col = (n0+nn)*16 + l15), row = quad*4 + reg.
#pragma unroll
  for (int i = 1; i <= 4; ++i) {
    if (i == 1) {
#pragma unroll
      for (int nn = 0; nn < 3; ++nn)
        if (nn < nmine)
#pragma unroll
          for (int r = 0; r < 4; ++r)
            Ys[0 * YSLOT + (quad * 4 + r) * YST + (n0 + nn) * 16 + l15] = acc[0][nn][r];
    }
#pragma unroll
    for (int nn = 0; nn < 3; ++nn)
      if (nn < nmine)
#pragma unroll
        for (int r = 0; r < 4; ++r)
          Ys[(i & 1) * YSLOT + (quad * 4 + r) * YST + (n0 + nn) * 16 + l15] = acc[i][nn][r];
    __syncthreads();
    for (int o = tid; o < 480; o += 256) {
      int r = o / 30;
      int j = o - 30 * r;
      int kw = j / 3 + 1;
      int p = j - (kw - 1) * 3;
      int base = 3 * (kw * (kw - 1)) / 2;
      float sum = 0.f;
      for (int d = 0; d < kw; ++d) {
        int rr = r - d;
        int slot = (rr >= 0) ? (i & 1) : ((i ^ 1) & 1);
        int lr = (rr >= 0) ? rr : (16 + rr);
        int colv = base + (kw - 1 - d) * 3 + p;
        sum += Ys[slot * YSLOT + lr * YST + colv];
      }
      int s = s0 + 16 * (i - 1) + r;
      out[((size_t)(b * S_DIM + s)) * 30 + j] = fmaxf(sum, 0.f);
    }
    __syncthreads();
  }
}

extern "C" void kernel_launch(void* const* d_in, const int* in_sizes, int n_in,
                              void* d_out, int out_size, void* d_ws, size_t ws_size,
                              hipStream_t stream) {
  const float* x = (const float*)d_in[0];
  WP wp;
  for (int k = 0; k < 10; ++k) wp.w[k] = (const float*)d_in[k + 1];
  _Float16* bt = (_Float16*)d_ws;                  // 176*512*2 B = 180224 B
  prep_kernel<<<NCOLP * C_DIM / 256, 256, 0, stream>>>(wp, bt);
  conv_kernel<<<32 * (S_DIM / M_OUT), 256, 0, stream>>>(x, bt, (float*)d_out);
}